// Round 1
// baseline (2341.413 us; speedup 1.0000x reference)
//
#include <hip/hip_runtime.h>
#include <stdint.h>

#define THETA 10.0

__device__ __forceinline__ double srm_val(int k) {
    double t = (double)k;
    return (t * 0.1) * exp(1.0 - t * 0.1);
}
__device__ __forceinline__ double ref_val(int d) {   // refractory kernel at offset d (1..32)
    double t = (double)d;
    return -20.0 * t * exp(1.0 - t);
}

// ---------------------------------------------------------------------------
// K1: px[n][c][t] = sum_k srm[k] * x[n][c][t-k]   (psp over time, pre-dense)
// grid: (64*156 rows) * 2 halves of t ; block 256
__global__ __launch_bounds__(256) void k_psp_time(const float* __restrict__ x,
                                                  double* __restrict__ px) {
    __shared__ double srm[100];
    int tid = threadIdx.x;
    if (tid < 100) srm[tid] = srm_val(tid);
    __syncthreads();
    int row = blockIdx.x >> 1;                 // n*156 + c
    int t = ((blockIdx.x & 1) << 8) + tid;
    if (t >= 500) return;
    const float* xr = x + (size_t)row * 500;
    int kmax = t < 99 ? t : 99;
    double acc = 0.0;
    for (int k = 0; k <= kmax; ++k) acc += srm[k] * (double)xr[t - k];
    px[(size_t)row * 500 + t] = acc;
}

// ---------------------------------------------------------------------------
// K2: fused dense (over c) + spike scan (over t) for layer A1.
// thread: lane_c = tid&3 (c-split of 156 into 4x39), row = tid>>2 (64 h per block)
// grid: (n=64, hb=8); block 256.  s1[n][t][h] uint8.
__global__ __launch_bounds__(256) void k_dense_scan_A(const double* __restrict__ px,
                                                      const float* __restrict__ w1,
                                                      uint8_t* __restrict__ s1) {
    __shared__ double lds[16 * 157];
    __shared__ double refk[32];
    int tid = threadIdx.x;
    if (tid < 32) refk[tid] = ref_val(tid + 1);
    int n = blockIdx.x, hb = blockIdx.y;
    int lc = tid & 3, row = tid >> 2;
    int h = hb * 64 + row;
    double w[39];
    const float* wr = w1 + h * 156 + lc * 39;
#pragma unroll
    for (int i = 0; i < 39; ++i) w[i] = (double)wr[i];
    const double* pxn = px + (size_t)n * 156 * 500;
    unsigned mask = 0;
    for (int t0 = 0; t0 < 500; t0 += 16) {
        int TT = (500 - t0 < 16) ? (500 - t0) : 16;
        __syncthreads();
        for (int e = tid; e < 156 * 16; e += 256) {
            int c = e >> 4, tt = e & 15;
            if (tt < TT) lds[tt * 157 + c] = pxn[(size_t)c * 500 + t0 + tt];
        }
        __syncthreads();
        for (int tt = 0; tt < TT; ++tt) {
            const double* p = lds + tt * 157 + lc * 39;
            double acc = 0.0;
#pragma unroll
            for (int i = 0; i < 39; ++i) acc += w[i] * p[i];
            acc += __shfl_xor(acc, 1);
            acc += __shfl_xor(acc, 2);
            double v = acc;
            unsigned m = mask;
            while (m) { int d = __builtin_ctz(m); v += refk[d]; m &= m - 1; }
            int s = (v >= THETA) ? 1 : 0;
            mask = (mask << 1) | (unsigned)s;
            if (lc == 0) s1[((size_t)n * 500 + (t0 + tt)) * 512 + h] = (uint8_t)s;
        }
    }
}

// ---------------------------------------------------------------------------
// K3/KB3: a[n][o][t] = sum_h w[o][h] * s[n][t][h]  (spikes are 0/1 bytes).
// thread per (n,t); 20 fp64 accumulators; w staged transposed as f32 in LDS.
__global__ __launch_bounds__(256) void k_dense2(const uint8_t* __restrict__ s,
                                                const float* __restrict__ w,
                                                double* __restrict__ a, int T) {
    __shared__ float wt[512 * 20];
    int tid = threadIdx.x;
    for (int e = tid; e < 512 * 20; e += 256) { int o = e / 512, h = e % 512; wt[h * 20 + o] = w[e]; }
    __syncthreads();
    int gid = blockIdx.x * 256 + tid;
    if (gid >= 64 * T) return;
    int n = gid / T, t = gid % T;
    const uint64_t* sw = (const uint64_t*)(s + ((size_t)n * T + t) * 512);
    double acc[20];
#pragma unroll
    for (int o = 0; o < 20; ++o) acc[o] = 0.0;
    for (int wd = 0; wd < 64; ++wd) {
        uint64_t mw = sw[wd] & 0x0101010101010101ULL;
        while (mw) {
            int b = __builtin_ctzll(mw);
            int h = wd * 8 + (b >> 3);
            const float* wp = wt + h * 20;
#pragma unroll
            for (int o = 0; o < 20; ++o) acc[o] += (double)wp[o];
            mw &= mw - 1;
        }
    }
#pragma unroll
    for (int o = 0; o < 20; ++o) a[((size_t)n * 20 + o) * T + t] = acc[o];
}

// ---------------------------------------------------------------------------
// K4a/KB4a: p[row][t] = sum_k srm[k]*a[row][t-k]  (row-parallel psp, fp64 rows)
__global__ __launch_bounds__(256) void k_psp_rows(const double* __restrict__ a,
                                                  double* __restrict__ p,
                                                  int T, int nrows) {
    __shared__ double srm[100];
    int tid = threadIdx.x;
    if (tid < 100) srm[tid] = srm_val(tid);
    __syncthreads();
    int gid = blockIdx.x * 256 + tid;
    if (gid >= nrows * T) return;
    int row = gid / T, t = gid % T;
    const double* ar = a + (size_t)row * T;
    int kmax = t < 99 ? t : 99;
    double acc = 0.0;
    for (int k = 0; k <= kmax; ++k) acc += srm[k] * ar[t - k];
    p[gid] = acc;
}

// ---------------------------------------------------------------------------
// K4b/KB4b: sequential spike scan per (n,o) row -> float 0/1 into d_out cols.
__global__ __launch_bounds__(256) void k_scan_out(const double* __restrict__ p,
                                                  float* __restrict__ out,
                                                  int T, int off) {
    __shared__ double refk[32];
    int tid = threadIdx.x;
    if (tid < 32) refk[tid] = ref_val(tid + 1);
    __syncthreads();
    int gid = blockIdx.x * 256 + tid;
    if (gid >= 1280) return;
    const double* pr = p + (size_t)gid * T;
    float* orow = out + (size_t)gid * 656 + off;
    unsigned mask = 0;
    for (int t = 0; t < T; ++t) {
        double v = pr[t];
        unsigned m = mask;
        while (m) { int d = __builtin_ctz(m); v += refk[d]; m &= m - 1; }
        int s = (v >= THETA) ? 1 : 0;
        mask = (mask << 1) | (unsigned)s;
        orow[t] = (float)s;
    }
}

// ---------------------------------------------------------------------------
// KB1: q[n][j][t] = sum_k srm[k] * x[n][perm[j-k]][t]   (psp over taxel axis)
__global__ __launch_bounds__(256) void k_psp_loc(const float* __restrict__ x,
                                                 const int* __restrict__ perm,
                                                 double* __restrict__ q) {
    __shared__ double srm[100];
    __shared__ int pl[156];
    int tid = threadIdx.x;
    if (tid < 100) srm[tid] = srm_val(tid);
    if (tid < 156) pl[tid] = perm[tid];
    __syncthreads();
    int b = blockIdx.x;
    int row = b >> 1;                  // n*156 + j
    int n = row / 156, j = row % 156;
    int t = ((b & 1) << 8) + tid;
    if (t >= 500) return;
    int kmax = j < 99 ? j : 99;
    double acc = 0.0;
    const float* xn = x + (size_t)n * 156 * 500;
    for (int k = 0; k <= kmax; ++k) {
        int c = pl[j - k];
        acc += srm[k] * (double)xn[(size_t)c * 500 + t];
    }
    q[(size_t)row * 500 + t] = acc;
}

// ---------------------------------------------------------------------------
// KB2: u1b[n][h][j] = sum_t w_loc1[h][t] * q[n][j][t]   (fp64 tiled GEMM)
// block: 64h x 64j tile, 4x4 micro-tile with interleaved lanes (conflict-free LDS)
__global__ __launch_bounds__(256) void k_gemm_loc(const double* __restrict__ q,
                                                  const float* __restrict__ wl1,
                                                  double* __restrict__ u1b) {
    __shared__ double At[16][65];
    __shared__ double Bt[16][65];
    int tid = threadIdx.x;
    int n = blockIdx.x, hb = blockIdx.y, jb = blockIdx.z;
    int tx = tid & 15, ty = tid >> 4;
    double acc[4][4];
#pragma unroll
    for (int i = 0; i < 4; ++i)
#pragma unroll
        for (int jj = 0; jj < 4; ++jj) acc[i][jj] = 0.0;
    const double* qn = q + (size_t)n * 156 * 500;
    for (int k0 = 0; k0 < 500; k0 += 16) {
        int KK = (500 - k0 < 16) ? (500 - k0) : 16;
        __syncthreads();
        for (int e = tid; e < 64 * 16; e += 256) {
            int hh = e >> 4, kk = e & 15;
            double v = 0.0;
            if (kk < KK) v = (double)wl1[(size_t)(hb * 64 + hh) * 500 + k0 + kk];
            At[kk][hh] = v;
        }
        for (int e = tid; e < 64 * 16; e += 256) {
            int jj2 = e >> 4, kk = e & 15;
            int j = jb * 64 + jj2;
            double v = 0.0;
            if (j < 156 && kk < KK) v = qn[(size_t)j * 500 + k0 + kk];
            Bt[kk][jj2] = v;
        }
        __syncthreads();
        for (int k = 0; k < KK; ++k) {
            double a0 = At[k][ty], a1 = At[k][ty + 16], a2v = At[k][ty + 32], a3 = At[k][ty + 48];
            double b0 = Bt[k][tx], b1 = Bt[k][tx + 16], b2 = Bt[k][tx + 32], b3 = Bt[k][tx + 48];
            acc[0][0] += a0 * b0; acc[0][1] += a0 * b1; acc[0][2] += a0 * b2; acc[0][3] += a0 * b3;
            acc[1][0] += a1 * b0; acc[1][1] += a1 * b1; acc[1][2] += a1 * b2; acc[1][3] += a1 * b3;
            acc[2][0] += a2v * b0; acc[2][1] += a2v * b1; acc[2][2] += a2v * b2; acc[2][3] += a2v * b3;
            acc[3][0] += a3 * b0; acc[3][1] += a3 * b1; acc[3][2] += a3 * b2; acc[3][3] += a3 * b3;
        }
    }
#pragma unroll
    for (int i = 0; i < 4; ++i) {
        int h = hb * 64 + ty + 16 * i;
#pragma unroll
        for (int jj = 0; jj < 4; ++jj) {
            int j = jb * 64 + tx + 16 * jj;
            if (j < 156) u1b[((size_t)n * 512 + h) * 156 + j] = acc[i][jj];
        }
    }
}

// ---------------------------------------------------------------------------
// KB2-scan: spike scan over j per (n,h) row -> s1b[n][j][h] uint8
__global__ __launch_bounds__(256) void k_scan_loc1(const double* __restrict__ u1b,
                                                   uint8_t* __restrict__ s1b) {
    __shared__ double refk[32];
    int tid = threadIdx.x;
    if (tid < 32) refk[tid] = ref_val(tid + 1);
    __syncthreads();
    int gid = blockIdx.x * 256 + tid;     // n*512 + h
    int n = gid >> 9, h = gid & 511;
    const double* ur = u1b + (size_t)gid * 156;
    unsigned mask = 0;
    for (int j = 0; j < 156; ++j) {
        double v = ur[j];
        unsigned m = mask;
        while (m) { int d = __builtin_ctz(m); v += refk[d]; m &= m - 1; }
        int s = (v >= THETA) ? 1 : 0;
        mask = (mask << 1) | (unsigned)s;
        s1b[((size_t)n * 156 + j) * 512 + h] = (uint8_t)s;
    }
}

// ---------------------------------------------------------------------------
extern "C" void kernel_launch(void* const* d_in, const int* in_sizes, int n_in,
                              void* d_out, int out_size, void* d_ws, size_t ws_size,
                              hipStream_t stream) {
    const float* x      = (const float*)d_in[0];
    const float* w_fc1  = (const float*)d_in[1];
    const float* w_fc2  = (const float*)d_in[2];
    const float* w_loc1 = (const float*)d_in[3];
    const float* w_loc2 = (const float*)d_in[4];
    const int*   perm   = (const int*)d_in[5];
    float* out = (float*)d_out;
    char* ws = (char*)d_ws;

    // workspace layout (bytes); path B overlays path A's dead buffers
    double*  px  = (double*)(ws + 0);              // 39,936,000 B (also q for path B)
    uint8_t* s1  = (uint8_t*)(ws + 39936000);      // 16,384,000 B
    double*  a2  = (double*)(ws + 56320000);       //  5,120,000 B
    double*  p2  = (double*)(ws + 61440000);       //  5,120,000 B
    double*  q   = px;
    double*  u1b = (double*)(ws + 39936000);       // 40,894,464 B (overlays s1/a2/p2)
    uint8_t* s1b = (uint8_t*)(ws + 80830464);      //  5,111,808 B
    double*  a2b = (double*)(ws + 85942272);       //  1,597,440 B
    double*  p2b = (double*)(ws + 87539712);       //  1,597,440 B
    (void)ws_size; (void)in_sizes; (void)n_in; (void)out_size;

    // ---- temporal path ----
    k_psp_time<<<19968, 256, 0, stream>>>(x, px);
    dim3 g2(64, 8);
    k_dense_scan_A<<<g2, 256, 0, stream>>>(px, w_fc1, s1);
    k_dense2<<<125, 256, 0, stream>>>(s1, w_fc2, a2, 500);
    k_psp_rows<<<2500, 256, 0, stream>>>(a2, p2, 500, 1280);
    k_scan_out<<<5, 256, 0, stream>>>(p2, out, 500, 0);

    // ---- location path ----
    k_psp_loc<<<19968, 256, 0, stream>>>(x, perm, q);
    dim3 gb(64, 8, 3);
    k_gemm_loc<<<gb, 256, 0, stream>>>(q, w_loc1, u1b);
    k_scan_loc1<<<128, 256, 0, stream>>>(u1b, s1b);
    k_dense2<<<39, 256, 0, stream>>>(s1b, w_loc2, a2b, 156);
    k_psp_rows<<<780, 256, 0, stream>>>(a2b, p2b, 156, 1280);
    k_scan_out<<<5, 256, 0, stream>>>(p2b, out, 156, 500);
}